// Round 1
// baseline (382.824 us; speedup 1.0000x reference)
//
#include <hip/hip_runtime.h>

// FullyConnectedTensorProduct: B=2^20 rows, per row:
//   s1=x1[0:8], v1=x1[8:32] as (8,3); s2,v2 same from x2
//   out0[w] = sum_{uv} s1[u]s2[v]W0[uvw] + (1/sqrt3) sum_{uv} (v1[u].v2[v]) W1[uvw]
//   out1[w,k] = sum_{uv} s1[u]v2[v,k]W2[uvw] + sum_{uv} v1[u,k]s2[v]W3[uvw]
//   out = ALPHA * concat(out0, out1.reshape(24))
// Weights are batch-uniform (8KB) -> scalar loads via constant cache.
// Factored contraction: ~2750 FMA/row. Memory floor ~64us @ 6.3 TB/s.

constexpr int TPB = 256;

__global__ __launch_bounds__(TPB) void tp_kernel(
    const float* __restrict__ x1,
    const float* __restrict__ x2,
    const float* __restrict__ wg,
    float* __restrict__ out,
    int batch)
{
    const float INV3  = 0.57735026918962576f;   // 1/sqrt(3)
    const float ALPHA = 0.088388347648318447f;  // 1/sqrt(128)

    int b = blockIdx.x * TPB + threadIdx.x;
    if (b >= batch) return;

    // ---- load inputs (8 x float4 each; rows are 128B aligned) ----
    float X1[32], X2[32];
    {
        const float4* p1 = (const float4*)(x1 + (size_t)b * 32);
        const float4* p2 = (const float4*)(x2 + (size_t)b * 32);
        #pragma unroll
        for (int j = 0; j < 8; ++j) {
            float4 t1 = p1[j];
            X1[4*j+0] = t1.x; X1[4*j+1] = t1.y; X1[4*j+2] = t1.z; X1[4*j+3] = t1.w;
            float4 t2 = p2[j];
            X2[4*j+0] = t2.x; X2[4*j+1] = t2.y; X2[4*j+2] = t2.z; X2[4*j+3] = t2.w;
        }
    }
    // s1[u] = X1[u], v1[u][k] = X1[8+u*3+k]; same for X2.

    float acc0[8], acc0b[8], acc1[8][3];
    #pragma unroll
    for (int t = 0; t < 8; ++t) {
        acc0[t] = 0.f; acc0b[t] = 0.f;
        acc1[t][0] = 0.f; acc1[t][1] = 0.f; acc1[t][2] = 0.f;
    }

    // ---- W0 (s1*s2) and W1 (v1.v2) -> out0 ----
    // per (v,u): p = s1[u]*s2[v]; d = v1[u].v2[v]; 8 contiguous weights each
    #pragma unroll
    for (int v = 0; v < 8; ++v) {
        #pragma unroll
        for (int u = 0; u < 8; ++u) {
            float p = X1[u] * X2[v];
            float d = X1[8+u*3+0]*X2[8+v*3+0]
                    + X1[8+u*3+1]*X2[8+v*3+1]
                    + X1[8+u*3+2]*X2[8+v*3+2];
            const float* w0 = wg + (u*64 + v*8);     // W0[u][v][0..7]
            #pragma unroll
            for (int t = 0; t < 8; ++t) {
                acc0[t]  += p * w0[t];
                acc0b[t] += d * w0[512 + t];         // W1[u][v][0..7]
            }
        }
    }

    // ---- W2: out1[w,k] += sum_v v2[v,k] * (sum_u s1[u] * W2[u,v,w]) ----
    #pragma unroll
    for (int v = 0; v < 8; ++v) {
        float a[8];
        #pragma unroll
        for (int t = 0; t < 8; ++t) a[t] = 0.f;
        #pragma unroll
        for (int u = 0; u < 8; ++u) {
            const float* w2 = wg + 1024 + (u*64 + v*8);
            float su = X1[u];
            #pragma unroll
            for (int t = 0; t < 8; ++t) a[t] += su * w2[t];
        }
        float c0 = X2[8+v*3+0], c1 = X2[8+v*3+1], c2 = X2[8+v*3+2];
        #pragma unroll
        for (int t = 0; t < 8; ++t) {
            acc1[t][0] += c0 * a[t];
            acc1[t][1] += c1 * a[t];
            acc1[t][2] += c2 * a[t];
        }
    }

    // ---- W3: out1[w,k] += sum_u v1[u,k] * (sum_v s2[v] * W3[u,v,w]) ----
    #pragma unroll
    for (int u = 0; u < 8; ++u) {
        float a[8];
        #pragma unroll
        for (int t = 0; t < 8; ++t) a[t] = 0.f;
        #pragma unroll
        for (int v = 0; v < 8; ++v) {
            const float* w3 = wg + 1536 + (u*64 + v*8);
            float sv = X2[v];
            #pragma unroll
            for (int t = 0; t < 8; ++t) a[t] += sv * w3[t];
        }
        float c0 = X1[8+u*3+0], c1 = X1[8+u*3+1], c2 = X1[8+u*3+2];
        #pragma unroll
        for (int t = 0; t < 8; ++t) {
            acc1[t][0] += c0 * a[t];
            acc1[t][1] += c1 * a[t];
            acc1[t][2] += c2 * a[t];
        }
    }

    // ---- epilogue: scale + pack + vectorized store ----
    float O[32];
    #pragma unroll
    for (int t = 0; t < 8; ++t) O[t] = ALPHA * (acc0[t] + INV3 * acc0b[t]);
    #pragma unroll
    for (int t = 0; t < 8; ++t) {
        O[8 + t*3 + 0] = ALPHA * acc1[t][0];
        O[8 + t*3 + 1] = ALPHA * acc1[t][1];
        O[8 + t*3 + 2] = ALPHA * acc1[t][2];
    }
    float4* po = (float4*)(out + (size_t)b * 32);
    #pragma unroll
    for (int j = 0; j < 8; ++j) {
        po[j] = make_float4(O[4*j+0], O[4*j+1], O[4*j+2], O[4*j+3]);
    }
}

extern "C" void kernel_launch(void* const* d_in, const int* in_sizes, int n_in,
                              void* d_out, int out_size, void* d_ws, size_t ws_size,
                              hipStream_t stream) {
    const float* x1 = (const float*)d_in[0];
    const float* x2 = (const float*)d_in[1];
    const float* wg = (const float*)d_in[2];
    float* out = (float*)d_out;

    int batch = in_sizes[0] / 32;
    dim3 grid((batch + TPB - 1) / TPB), block(TPB);
    hipLaunchKernelGGL(tp_kernel, grid, block, 0, stream, x1, x2, wg, out, batch);
}